// Round 8
// baseline (147.791 us; speedup 1.0000x reference)
//
#include <hip/hip_runtime.h>
#include <hip/hip_bf16.h>

// EfficientAttention: x(4,256,64,64) -> qkv(192ch) -> attn(N=4096,c=64) -> proj(256ch)
// k_prep: qkv weights fp32->bf16 frag layout (QSC folded into Q rows/bias).
// k_qkv (R5): 256 blocks x 64-token tiles, 768 thr (12 waves). Wave = ONE
//         (o-tile, chunk) task; 16 weight frags hoisted pre-barrier.
//   Qf/Kf: [b][chunk32][kk(4)][lane(64)][8]
//   Vf   : [b][chunk32][ct(2)ks(2)][lane(64)][j(8)] = producer reg order
// k_attn (R8): FLASH-STYLE 64 blocks x 256 q-rows, 8 waves; wave OWNS one
//         32-q subtile and iterates ALL 128 k-chunks. Why: R0-R7 showed every
//         staging/pipelining structure costs the same (~15 B/cyc/CU K/V
//         service; time = bytes/rate), so the lever is TRAFFIC: 4x more q-rows
//         per block => 4x fewer K/V re-reads (256MB -> 64MB). O and den are
//         pure sums (no max-subtraction) so they accumulate fully in-register:
//         NO Oacc atomics, same 32-VGPR accumulator/wave. K+V staged in LDS
//         (16 tiles x 8 chunks, 64KB/tile dbuf, one full-tile-covered barrier
//         per tile = R0-proven). New floor: MFMA issue (~28us at 64 CUs) --
//         if MfmaUtil jumps to ~50%+ this is confirmed and R9 k-splits.

#define N_TOK 4096
#define CDIM  64
#define DIM   256
#define NBAT  4

typedef __attribute__((ext_vector_type(8)))  short          short8;
typedef __attribute__((ext_vector_type(8)))  unsigned short ushort8_t;
typedef __attribute__((ext_vector_type(4)))  unsigned short ushort4_t;
typedef __attribute__((ext_vector_type(4)))  unsigned int   uint4_t;
typedef __attribute__((ext_vector_type(4)))  float          float4_t;
typedef __attribute__((ext_vector_type(16))) float          float16_t;

#if __has_builtin(__builtin_amdgcn_exp2f)
#define QSC  0.18033688011112042f   /* 0.125 * log2(e): p = exp2(s) */
#define PEXP(x) __builtin_amdgcn_exp2f(x)
#else
#define QSC  0.125f
#define PEXP(x) __expf(x)
#endif

__device__ __forceinline__ unsigned short f2bf(float f) {
  unsigned int u = __builtin_bit_cast(unsigned int, f);
  u += 0x7fffu + ((u >> 16) & 1u);            // RNE
  return (unsigned short)(u >> 16);
}

// packed f32x2 -> bf16x2 dword (v_cvt_pk_bf16_f32 on gfx950, RNE)
__device__ __forceinline__ unsigned int pkcv(float a, float b) {
  __hip_bfloat162 h = __float22bfloat162_rn(make_float2(a, b));
  unsigned int r; __builtin_memcpy(&r, &h, 4); return r;
}

__device__ __forceinline__ short8 ld8(const unsigned short* p) {
  return __builtin_bit_cast(short8, *(const ushort8_t*)p);
}

__device__ __forceinline__ short8 pack8f(float4_t a, float4_t b) {
  uint4_t u;
  u[0] = pkcv(a[0], a[1]); u[1] = pkcv(a[2], a[3]);
  u[2] = pkcv(b[0], b[1]); u[3] = pkcv(b[2], b[3]);
  return __builtin_bit_cast(short8, u);
}

__device__ __forceinline__ float16_t z16() {
  float16_t r;
#pragma unroll
  for (int i = 0; i < 16; ++i) r[i] = 0.0f;
  return r;
}

// async global->LDS DMA: 64 lanes x 16B; LDS dst = wave-uniform base (+lane*16 by HW)
typedef __attribute__((address_space(1))) const void* gvp;
typedef __attribute__((address_space(3))) void*       lvp;
__device__ __forceinline__ void dma16(const unsigned short* g, unsigned short* l) {
  __builtin_amdgcn_global_load_lds((gvp)g, (lvp)l, 16, 0, 0);
}

#define MFMA(a, b, c) __builtin_amdgcn_mfma_f32_32x32x16_bf16((a), (b), (c), 0, 0, 0)

// ws layout (u16 units)
#define QOFF  0                // 4*128*4*512 = 1048576 each
#define KOFF  1048576
#define VOFF  2097152
#define WQOFF 3145728          // 192*256
#define BSOFF 3194880          // scaled qkv bias, fp32 (192)

// ---------------------------------------------------------------------------
// k_prep: grid 24 x 256. qkv_w -> bf16 frag layout (Q rows scaled by QSC);
// bias -> fp32 with Q-scale fold.
// ---------------------------------------------------------------------------
__global__ void k_prep(const float* __restrict__ qw, const float* __restrict__ qb,
                       unsigned short* __restrict__ wqs, float* __restrict__ bs)
{
  const int g = blockIdx.x * 256 + threadIdx.x;   // 0..6143
  {
    const int lane = g & 63, grp = g >> 6;
    const int w6 = grp >> 4, kk = grp & 15;
    const int o = w6 * 32 + (lane & 31);
    const int c = kk * 16 + (lane >> 5) * 8;
    const float sc = (o < 64) ? QSC : 1.0f;
    const float* src = qw + o * 256 + c;
    ushort8_t u;
#pragma unroll
    for (int j = 0; j < 8; ++j) u[j] = f2bf(src[j] * sc);
    *(ushort8_t*)(wqs + g * 8) = u;
  }
  if (g < 48) {
    float4_t f = *(const float4_t*)(qb + g * 4);
    float4_t o;
#pragma unroll
    for (int j = 0; j < 4; ++j) o[j] = f[j] * ((g * 4 + j) < 64 ? QSC : 1.0f);
    *(float4_t*)(bs + g * 4) = o;
  }
}

// ---------------------------------------------------------------------------
// k_qkv: grid 256 x 768 thr (12 waves). Block: 64-token tile, all 192 o.
// Wave w: o-tile (w>>1), chunk (w&1). Weight frags hoisted to wf[16] before
// the barrier (overlaps x staging). Waves 0-7 (Q,K): C[o rows][n cols];
// waves 8-11 (V): swapped operands -> C[token rows][c cols].
// ---------------------------------------------------------------------------
#define RS 132   // Xl row stride in dwords

__global__ __launch_bounds__(768, 3) void k_qkv(
    const float* __restrict__ x, const unsigned short* __restrict__ wqs,
    const float* __restrict__ bs, unsigned short* __restrict__ Qf,
    unsigned short* __restrict__ Kf, unsigned short* __restrict__ Vf)
{
  __shared__ unsigned int Xl[64 * RS];
  const int id = blockIdx.x;
  const int b  = (id >> 1) & 3;
  const int nt = (id & 1) | ((id >> 3) << 1);   // 0..63 (64-token tile)
  const int t  = threadIdx.x;
  const int n0g = nt * 64;

  if (t < 512) {
    const int n0  = (t & 15) * 4;
    const int cpb = t >> 4;                      // 0..31
#pragma unroll
    for (int p = 0; p < 4; ++p) {
      const int cp = cpb + 32 * p, c = cp * 2;
      const float* xb = x + (((size_t)(b * DIM + c)) << 12) + n0g + n0;
      float4_t a = *(const float4_t*)xb;
      float4_t d = *(const float4_t*)(xb + 4096);
#pragma unroll
      for (int j = 0; j < 4; ++j)
        Xl[(n0 + j) * RS + cp] = pkcv(a[j], d[j]);
    }
  }

  const int w = t >> 6, lane = t & 63, l31 = lane & 31, lh = lane >> 5;
  const int ot = w >> 1, sub = w & 1;
  const int ch = nt * 2 + sub;                   // global 32-token chunk

  // hoist all 16 weight frags (independent L2 loads, issued pre-barrier)
  const unsigned short* wrow = wqs + ((ot * 16) << 9) + lane * 8;
  short8 wf[16];
#pragma unroll
  for (int kk = 0; kk < 16; ++kk) wf[kk] = ld8(wrow + (kk << 9));

  __syncthreads();

  const unsigned int* xr = &Xl[(sub * 32 + l31) * RS + lh * 4];

  float16_t a0 = z16();
  if (ot < 4) {
#pragma unroll
    for (int kk = 0; kk < 16; ++kk) {
      short8 xf = __builtin_bit_cast(short8, *(const uint4_t*)(xr + kk * 8));
      a0 = MFMA(wf[kk], xf, a0);                 // C[o rows][n cols]
    }
  } else {
#pragma unroll
    for (int kk = 0; kk < 16; ++kk) {
      short8 xf = __builtin_bit_cast(short8, *(const uint4_t*)(xr + kk * 8));
      a0 = MFMA(xf, wf[kk], a0);                 // C[token rows][c cols]
    }
  }

  if (ot < 4) {
    unsigned short* dst = (ot < 2) ? Qf : Kf;
    const int w2 = ot & 1;                       // c64-half of Q or K
#pragma unroll
    for (int p = 0; p < 4; ++p) {
      const int o = ot * 32 + p * 8 + lh * 4;    // global qkv channel
      float4_t bv = *(const float4_t*)(bs + o);
      ushort4_t pk4;
#pragma unroll
      for (int q = 0; q < 4; ++q) pk4[q] = f2bf(a0[p * 4 + q] + bv[q]);
      const int kkt = w2 * 2 + (p >> 1);
      *(ushort4_t*)(dst + ((((b * 128 + ch) * 4 + kkt) << 9)
                           + (l31 + 32 * (p & 1)) * 8 + lh * 4)) = pk4;
    }
  } else {
    const int ct = ot - 4;                       // c-group of V
    const float bvs = bs[128 + ct * 32 + l31];
#pragma unroll
    for (int ks = 0; ks < 2; ++ks) {
      ushort8_t pk8;
#pragma unroll
      for (int j = 0; j < 8; ++j) pk8[j] = f2bf(a0[ks * 8 + j] + bvs);
      *(ushort8_t*)(Vf + ((((b * 128 + ch) * 4 + ct * 2 + ks) << 9)
                          + lane * 8)) = pk8;
    }
  }
}

// ---------------------------------------------------------------------------
// k_attn: grid 64 x 512 thr (8 waves). Block: 256 q-rows (q-group qt, 0..15).
// Wave wv owns q-chunk qt*8+wv (32 rows): O + den accumulate fully in-register
// across ALL 128 k-chunks. K/V staged in LDS: 16 tiles x 8 chunks (64KB/tile,
// 2x dbuf = 128KB); wave wv stages chunk wv of each tile (8 dma16). One
// barrier per tile; full tile of compute covers each DMA drain. Epilogue:
// shfl-broadcast 1/den, write Ol (reusing staging LDS), fused proj.
// ---------------------------------------------------------------------------
#define OLS  72    // Ol row stride (bf16)

__global__ __launch_bounds__(512, 1) void k_attn(
    const unsigned short* __restrict__ Qf, const unsigned short* __restrict__ Kf,
    const unsigned short* __restrict__ Vf, const float* __restrict__ pw,
    const float* __restrict__ pb, float* __restrict__ out)
{
  __shared__ __align__(16) unsigned short KV[2][2][16384]; // [buf][K|V][8ch*2048]

  const int id = blockIdx.x;
  const int b  = (id >> 1) & 3;                      // batch pinned to XCD pair
  const int qt = (id & 1) | ((id >> 3) << 1);        // 0..15 (256-token q-group)
  const int t  = threadIdx.x;
  const int wv = t >> 6, lane = t & 63, l31 = lane & 31, lh = lane >> 5;

  // Q frags of the wave's OWN 32-q chunk (QSC pre-folded)
  const int cq = qt * 8 + wv;
  short8 qf[4];
#pragma unroll
  for (int kk = 0; kk < 4; ++kk)
    qf[kk] = ld8(Qf + (((b * 128 + cq) * 4 + kk) << 9) + lane * 8);

  // staging role: wave stages chunk wv (K + V) of each 8-chunk tile
  const unsigned short* sgK = Kf + (((size_t)(b * 128 + wv)) << 11) + lane * 8;
  const unsigned short* sgV = Vf + (((size_t)(b * 128 + wv)) << 11) + lane * 8;

  // stage tile 0 into buf 0
#pragma unroll
  for (int kk = 0; kk < 4; ++kk)
    dma16(sgK + (kk << 9), &KV[0][0][(wv << 11) + (kk << 9)]);
#pragma unroll
  for (int kk = 0; kk < 4; ++kk)
    dma16(sgV + (kk << 9), &KV[0][1][(wv << 11) + (kk << 9)]);

  float16_t oc0 = z16(), oc1 = z16();   // O partial: rows = q, cols = ct*32+l31
  float den = 0.0f;

  __syncthreads();   // tile 0 resident

  for (int t16 = 0; t16 < 16; ++t16) {
    const int cur = t16 & 1;

    // stage tile t16+1 (drained at the NEXT barrier, a full tile later)
    if (t16 < 15) {
      const size_t go = ((size_t)(t16 + 1)) << 14;
#pragma unroll
      for (int kk = 0; kk < 4; ++kk)
        dma16(sgK + go + (kk << 9), &KV[cur ^ 1][0][(wv << 11) + (kk << 9)]);
#pragma unroll
      for (int kk = 0; kk < 4; ++kk)
        dma16(sgV + go + (kk << 9), &KV[cur ^ 1][1][(wv << 11) + (kk << 9)]);
    }

#pragma unroll
    for (int cc = 0; cc < 8; ++cc) {
      const unsigned short* kl = &KV[cur][0][cc << 11];
      const unsigned short* vl = &KV[cur][1][cc << 11];

      short8 kf0 = ld8(kl + lane * 8);
      short8 kf1 = ld8(kl + 512 + lane * 8);
      short8 kf2 = ld8(kl + 1024 + lane * 8);
      short8 kf3 = ld8(kl + 1536 + lane * 8);

      // S^T tile: lane col n = l31 (q-row), row m = (e&3)+8*(e>>2)+4*lh
      float16_t s = z16();
      s = MFMA(kf0, qf[0], s);
      s = MFMA(kf1, qf[1], s);
      s = MFMA(kf2, qf[2], s);
      s = MFMA(kf3, qf[3], s);

      float p[16];
#pragma unroll
      for (int e = 0; e < 16; ++e) p[e] = PEXP(s[e]);
      {
        float d0 = (p[0] + p[1]) + (p[2] + p[3]);
        float d1 = (p[4] + p[5]) + (p[6] + p[7]);
        float d2 = (p[8] + p[9]) + (p[10] + p[11]);
        float d3 = (p[12] + p[13]) + (p[14] + p[15]);
        den += (d0 + d1) + (d2 + d3);
      }

      // S regs ARE the O-MFMA A-operand (V k-slots pre-permuted at production)
      uint4_t w0, w1;
#pragma unroll
      for (int j = 0; j < 4; ++j) {
        w0[j] = pkcv(p[2 * j], p[2 * j + 1]);
        w1[j] = pkcv(p[8 + 2 * j], p[9 + 2 * j]);
      }
      short8 pf0 = __builtin_bit_cast(short8, w0);   // m 0..15 of chunk
      short8 pf1 = __builtin_bit_cast(short8, w1);   // m 16..31

      short8 vf0 = ld8(vl + lane * 8);               // ct0 ks0
      short8 vf1 = ld8(vl + 512 + lane * 8);         // ct0 ks1
      short8 vf2 = ld8(vl + 1024 + lane * 8);        // ct1 ks0
      short8 vf3 = ld8(vl + 1536 + lane * 8);        // ct1 ks1

      oc0 = MFMA(pf0, vf0, oc0);
      oc0 = MFMA(pf1, vf1, oc0);
      oc1 = MFMA(pf0, vf2, oc1);
      oc1 = MFMA(pf1, vf3, oc1);
    }

    __syncthreads();   // drains next-tile DMA + frees cur buffer
  }

  // full denominator per q-row (lane l31 and l31+32 hold halves)
  den += __shfl_xor(den, 32);
  const float inv = 1.0f / den;                      // valid in lanes of row l31

  // normalize in-register (shfl-broadcast row inverses) -> Ol (LDS reuse)
  unsigned short* Ol = &KV[0][0][0];                 // 256 x OLS bf16 = 36KB
#pragma unroll
  for (int e = 0; e < 16; ++e) {
    const int r = (e & 3) + 8 * (e >> 2) + 4 * lh;   // q-row within subtile
    const float rv = __shfl(inv, r);                 // 1/den of row r
    Ol[(wv * 32 + r) * OLS + l31]      = f2bf(oc0[e] * rv);
    Ol[(wv * 32 + r) * OLS + 32 + l31] = f2bf(oc1[e] * rv);
  }
  __syncthreads();

  // fused proj: wave wv -> o-tile wv (32 o) x all 256 n rows; raw fp32 W
  const float* pwrow = pw + (wv * 32 + l31) * 64 + lh * 8;
  short8 af[4];
#pragma unroll
  for (int kk = 0; kk < 4; ++kk) {
    float4_t wa = *(const float4_t*)(pwrow + kk * 16);
    float4_t wb = *(const float4_t*)(pwrow + kk * 16 + 4);
    af[kk] = pack8f(wa, wb);
  }
  float bv[16];
#pragma unroll
  for (int e = 0; e < 16; ++e)
    bv[e] = pb[wv * 32 + (e & 3) + 8 * (e >> 2) + 4 * lh];

  const int n0 = qt * 256;
#pragma unroll
  for (int ns = 0; ns < 8; ++ns) {
    float16_t f = z16();
#pragma unroll
    for (int kk = 0; kk < 4; ++kk) {
      short8 bfr = ld8(&Ol[(ns * 32 + l31) * OLS + kk * 16 + lh * 8]);
      f = MFMA(af[kk], bfr, f);
    }
#pragma unroll
    for (int e = 0; e < 16; ++e) {
      const int o = wv * 32 + (e & 3) + 8 * (e >> 2) + 4 * lh;
      out[((b * 256 + o) << 12) + n0 + ns * 32 + l31] = f[e] + bv[e];
    }
  }
}

extern "C" void kernel_launch(void* const* d_in, const int* in_sizes, int n_in,
                              void* d_out, int out_size, void* d_ws, size_t ws_size,
                              hipStream_t stream) {
  const float* x      = (const float*)d_in[0];
  const float* qkv_w  = (const float*)d_in[1];
  const float* qkv_b  = (const float*)d_in[2];
  const float* proj_w = (const float*)d_in[3];
  const float* proj_b = (const float*)d_in[4];
  float* out = (float*)d_out;

  unsigned short* ws  = (unsigned short*)d_ws;
  unsigned short* qf  = ws + QOFF;
  unsigned short* kf  = ws + KOFF;
  unsigned short* vf  = ws + VOFF;
  unsigned short* wqs = ws + WQOFF;
  float*          bs  = (float*)(ws + BSOFF);

  k_prep<<<24, 256, 0, stream>>>(qkv_w, qkv_b, wqs, bs);
  k_qkv<<<256, 768, 0, stream>>>(x, wqs, bs, qf, kf, vf);
  k_attn<<<64, 512, 0, stream>>>(qf, kf, vf, proj_w, proj_b, out);
}

// Round 9
// 146.151 us; speedup vs baseline: 1.0112x; 1.0112x over previous
//
#include <hip/hip_runtime.h>
#include <hip/hip_bf16.h>

// EfficientAttention: x(4,256,64,64) -> qkv(192ch) -> attn(N=4096,c=64) -> proj(256ch)
// k_prep: qkv weights fp32->bf16 frag layout (QSC folded into Q rows/bias).
// k_qkv (R5): 256 blocks x 64-token tiles, 768 thr (12 waves). Wave = ONE
//         (o-tile, chunk) task; 16 weight frags hoisted pre-barrier.
//   Qf/Kf: [b][chunk32][kk(4)][lane(64)][8]
//   Vf   : [b][chunk32][ct(2)ks(2)][lane(64)][j(8)] = producer reg order
// k_attn (R9): 256 blocks x 1024 thr (16 waves, 4/SIMD), NO loop barriers,
//         direct global->reg K/V. Unified R0-R8 theory: per-chunk dep chain
//         (~500-700cyc) is ~3x its issue work (~190cyc) and every prior
//         variant ran <=2 waves/SIMD (R2's 4/SIMD had lockstep barriers,
//         R4's spilled at cap 64) -> ~27% issue efficiency everywhere.
//         Fix = the untested quadrant {4 waves/SIMD, no barriers, no spill}:
//         each wave owns ONE q-subtile (halves persistent state: qf 16 +
//         acc 32 ~ 60 VGPR persistent, ~125 peak < 128 cap) and one of 8
//         m-streams (16 chunks). Wave pairs reload the same K/V chunks
//         (512MB L2, ~2TB/s/XCD -- under ceiling). Epilogue = R2's 16-wave
//         LDS-atomic combine + fused proj.

#define N_TOK 4096
#define CDIM  64
#define DIM   256
#define NBAT  4

typedef __attribute__((ext_vector_type(8)))  short          short8;
typedef __attribute__((ext_vector_type(8)))  unsigned short ushort8_t;
typedef __attribute__((ext_vector_type(4)))  unsigned short ushort4_t;
typedef __attribute__((ext_vector_type(4)))  unsigned int   uint4_t;
typedef __attribute__((ext_vector_type(4)))  float          float4_t;
typedef __attribute__((ext_vector_type(16))) float          float16_t;

#if __has_builtin(__builtin_amdgcn_exp2f)
#define QSC  0.18033688011112042f   /* 0.125 * log2(e): p = exp2(s) */
#define PEXP(x) __builtin_amdgcn_exp2f(x)
#else
#define QSC  0.125f
#define PEXP(x) __expf(x)
#endif

__device__ __forceinline__ unsigned short f2bf(float f) {
  unsigned int u = __builtin_bit_cast(unsigned int, f);
  u += 0x7fffu + ((u >> 16) & 1u);            // RNE
  return (unsigned short)(u >> 16);
}

// packed f32x2 -> bf16x2 dword (v_cvt_pk_bf16_f32 on gfx950, RNE)
__device__ __forceinline__ unsigned int pkcv(float a, float b) {
  __hip_bfloat162 h = __float22bfloat162_rn(make_float2(a, b));
  unsigned int r; __builtin_memcpy(&r, &h, 4); return r;
}

__device__ __forceinline__ short8 ld8(const unsigned short* p) {
  return __builtin_bit_cast(short8, *(const ushort8_t*)p);
}

__device__ __forceinline__ short8 pack8f(float4_t a, float4_t b) {
  uint4_t u;
  u[0] = pkcv(a[0], a[1]); u[1] = pkcv(a[2], a[3]);
  u[2] = pkcv(b[0], b[1]); u[3] = pkcv(b[2], b[3]);
  return __builtin_bit_cast(short8, u);
}

__device__ __forceinline__ float16_t z16() {
  float16_t r;
#pragma unroll
  for (int i = 0; i < 16; ++i) r[i] = 0.0f;
  return r;
}

#define MFMA(a, b, c) __builtin_amdgcn_mfma_f32_32x32x16_bf16((a), (b), (c), 0, 0, 0)

// ws layout (u16 units)
#define QOFF  0                // 4*128*4*512 = 1048576 each
#define KOFF  1048576
#define VOFF  2097152
#define WQOFF 3145728          // 192*256
#define BSOFF 3194880          // scaled qkv bias, fp32 (192)

// ---------------------------------------------------------------------------
// k_prep: grid 24 x 256. qkv_w -> bf16 frag layout (Q rows scaled by QSC);
// bias -> fp32 with Q-scale fold.
// ---------------------------------------------------------------------------
__global__ void k_prep(const float* __restrict__ qw, const float* __restrict__ qb,
                       unsigned short* __restrict__ wqs, float* __restrict__ bs)
{
  const int g = blockIdx.x * 256 + threadIdx.x;   // 0..6143
  {
    const int lane = g & 63, grp = g >> 6;
    const int w6 = grp >> 4, kk = grp & 15;
    const int o = w6 * 32 + (lane & 31);
    const int c = kk * 16 + (lane >> 5) * 8;
    const float sc = (o < 64) ? QSC : 1.0f;
    const float* src = qw + o * 256 + c;
    ushort8_t u;
#pragma unroll
    for (int j = 0; j < 8; ++j) u[j] = f2bf(src[j] * sc);
    *(ushort8_t*)(wqs + g * 8) = u;
  }
  if (g < 48) {
    float4_t f = *(const float4_t*)(qb + g * 4);
    float4_t o;
#pragma unroll
    for (int j = 0; j < 4; ++j) o[j] = f[j] * ((g * 4 + j) < 64 ? QSC : 1.0f);
    *(float4_t*)(bs + g * 4) = o;
  }
}

// ---------------------------------------------------------------------------
// k_qkv: grid 256 x 768 thr (12 waves). Block: 64-token tile, all 192 o.
// Wave w: o-tile (w>>1), chunk (w&1). Weight frags hoisted to wf[16] before
// the barrier (overlaps x staging). Waves 0-7 (Q,K): C[o rows][n cols];
// waves 8-11 (V): swapped operands -> C[token rows][c cols].
// ---------------------------------------------------------------------------
#define RS 132   // Xl row stride in dwords

__global__ __launch_bounds__(768, 3) void k_qkv(
    const float* __restrict__ x, const unsigned short* __restrict__ wqs,
    const float* __restrict__ bs, unsigned short* __restrict__ Qf,
    unsigned short* __restrict__ Kf, unsigned short* __restrict__ Vf)
{
  __shared__ unsigned int Xl[64 * RS];
  const int id = blockIdx.x;
  const int b  = (id >> 1) & 3;
  const int nt = (id & 1) | ((id >> 3) << 1);   // 0..63 (64-token tile)
  const int t  = threadIdx.x;
  const int n0g = nt * 64;

  if (t < 512) {
    const int n0  = (t & 15) * 4;
    const int cpb = t >> 4;                      // 0..31
#pragma unroll
    for (int p = 0; p < 4; ++p) {
      const int cp = cpb + 32 * p, c = cp * 2;
      const float* xb = x + (((size_t)(b * DIM + c)) << 12) + n0g + n0;
      float4_t a = *(const float4_t*)xb;
      float4_t d = *(const float4_t*)(xb + 4096);
#pragma unroll
      for (int j = 0; j < 4; ++j)
        Xl[(n0 + j) * RS + cp] = pkcv(a[j], d[j]);
    }
  }

  const int w = t >> 6, lane = t & 63, l31 = lane & 31, lh = lane >> 5;
  const int ot = w >> 1, sub = w & 1;
  const int ch = nt * 2 + sub;                   // global 32-token chunk

  // hoist all 16 weight frags (independent L2 loads, issued pre-barrier)
  const unsigned short* wrow = wqs + ((ot * 16) << 9) + lane * 8;
  short8 wf[16];
#pragma unroll
  for (int kk = 0; kk < 16; ++kk) wf[kk] = ld8(wrow + (kk << 9));

  __syncthreads();

  const unsigned int* xr = &Xl[(sub * 32 + l31) * RS + lh * 4];

  float16_t a0 = z16();
  if (ot < 4) {
#pragma unroll
    for (int kk = 0; kk < 16; ++kk) {
      short8 xf = __builtin_bit_cast(short8, *(const uint4_t*)(xr + kk * 8));
      a0 = MFMA(wf[kk], xf, a0);                 // C[o rows][n cols]
    }
  } else {
#pragma unroll
    for (int kk = 0; kk < 16; ++kk) {
      short8 xf = __builtin_bit_cast(short8, *(const uint4_t*)(xr + kk * 8));
      a0 = MFMA(xf, wf[kk], a0);                 // C[token rows][c cols]
    }
  }

  if (ot < 4) {
    unsigned short* dst = (ot < 2) ? Qf : Kf;
    const int w2 = ot & 1;                       // c64-half of Q or K
#pragma unroll
    for (int p = 0; p < 4; ++p) {
      const int o = ot * 32 + p * 8 + lh * 4;    // global qkv channel
      float4_t bv = *(const float4_t*)(bs + o);
      ushort4_t pk4;
#pragma unroll
      for (int q = 0; q < 4; ++q) pk4[q] = f2bf(a0[p * 4 + q] + bv[q]);
      const int kkt = w2 * 2 + (p >> 1);
      *(ushort4_t*)(dst + ((((b * 128 + ch) * 4 + kkt) << 9)
                           + (l31 + 32 * (p & 1)) * 8 + lh * 4)) = pk4;
    }
  } else {
    const int ct = ot - 4;                       // c-group of V
    const float bvs = bs[128 + ct * 32 + l31];
#pragma unroll
    for (int ks = 0; ks < 2; ++ks) {
      ushort8_t pk8;
#pragma unroll
      for (int j = 0; j < 8; ++j) pk8[j] = f2bf(a0[ks * 8 + j] + bvs);
      *(ushort8_t*)(Vf + ((((b * 128 + ch) * 4 + ct * 2 + ks) << 9)
                          + lane * 8)) = pk8;
    }
  }
}

// ---------------------------------------------------------------------------
// k_attn: grid 256 x 1024 thr (16 waves, 4/SIMD). Block: 64 q-rows.
// Wave wv: q-subtile (wv&1), m-stream (wv>>1): k-chunks {8*it + (wv>>1)},
// it=0..15, K/V direct global->reg (L2-resident; wave pairs share lines).
// ZERO loop barriers. Epilogue: LDS-atomic combine, normalize, fused proj.
// ---------------------------------------------------------------------------
#define OS   68    // Oacc row stride (fp32)
#define OLS  72    // Ol row stride (bf16)
#define NACC (64 * OS + 64)

__global__ __launch_bounds__(1024) void k_attn(
    const unsigned short* __restrict__ Qf, const unsigned short* __restrict__ Kf,
    const unsigned short* __restrict__ Vf, const float* __restrict__ pw,
    const float* __restrict__ pb, float* __restrict__ out)
{
  __shared__ float Oacc[NACC];                             // O[n][c] + den tail
  __shared__ __align__(16) unsigned short Ol[64 * OLS];

  const int id = blockIdx.x;
  const int b  = (id >> 1) & 3;
  const int nt = (id & 1) | ((id >> 3) << 1);        // 0..63
  const int t  = threadIdx.x;
  const int wv = t >> 6, lane = t & 63, l31 = lane & 31, lh = lane >> 5;
  const int nsub = wv & 1, ms = wv >> 1;             // q-subtile, m-stream

  for (int i = t; i < NACC; i += 1024) Oacc[i] = 0.0f;

  // Q frags of the wave's q-subtile (QSC pre-folded)
  short8 qf[4];
#pragma unroll
  for (int kk = 0; kk < 4; ++kk)
    qf[kk] = ld8(Qf + (((b * 128 + nt * 2 + nsub) * 4 + kk) << 9) + lane * 8);

  // wave's chunk base: chunk ms of batch b; advance 8 chunks (1<<14 u16)/iter
  const unsigned short* kb = Kf + (((size_t)(b * 128 + ms)) << 11) + lane * 8;
  const unsigned short* vb = Vf + (((size_t)(b * 128 + ms)) << 11) + lane * 8;

  float16_t oc0 = z16(), oc1 = z16();   // ct 0/1
  float den = 0.0f;

  __syncthreads();   // Oacc zeroed before epilogue atomics

  for (int it = 0; it < 16; ++it) {
    const size_t o = ((size_t)it) << 14;
    short8 kf0 = ld8(kb + o),        kf1 = ld8(kb + o + 512);
    short8 kf2 = ld8(kb + o + 1024), kf3 = ld8(kb + o + 1536);
    short8 vf0 = ld8(vb + o),        vf1 = ld8(vb + o + 512);
    short8 vf2 = ld8(vb + o + 1024), vf3 = ld8(vb + o + 1536);

    // S^T tile: lane col n = l31, row m = (e&3)+8*(e>>2)+4*lh
    float16_t s = z16();
    s = MFMA(kf0, qf[0], s);
    s = MFMA(kf1, qf[1], s);
    s = MFMA(kf2, qf[2], s);
    s = MFMA(kf3, qf[3], s);

    float p[16];
#pragma unroll
    for (int e = 0; e < 16; ++e) p[e] = PEXP(s[e]);
    {
      float d0 = (p[0] + p[1]) + (p[2] + p[3]);
      float d1 = (p[4] + p[5]) + (p[6] + p[7]);
      float d2 = (p[8] + p[9]) + (p[10] + p[11]);
      float d3 = (p[12] + p[13]) + (p[14] + p[15]);
      den += (d0 + d1) + (d2 + d3);
    }

    // S regs ARE the O-MFMA A-operand (V k-slots pre-permuted at production)
    uint4_t w0, w1;
#pragma unroll
    for (int j = 0; j < 4; ++j) {
      w0[j] = pkcv(p[2 * j], p[2 * j + 1]);
      w1[j] = pkcv(p[8 + 2 * j], p[9 + 2 * j]);
    }
    short8 pf0 = __builtin_bit_cast(short8, w0);   // m 0..15 of chunk
    short8 pf1 = __builtin_bit_cast(short8, w1);   // m 16..31

    oc0 = MFMA(pf0, vf0, oc0);
    oc0 = MFMA(pf1, vf1, oc0);
    oc1 = MFMA(pf0, vf2, oc1);
    oc1 = MFMA(pf1, vf3, oc1);
  }

  den += __shfl_xor(den, 32);   // combine lane halves (m coverage)

  // combine 8 m-stream partials per subtile: O[n][c] (+ den) via LDS atomics
#pragma unroll
  for (int ct = 0; ct < 2; ++ct) {
    const float16_t& oa = ct ? oc1 : oc0;
    const int cc = ct * 32 + l31;
#pragma unroll
    for (int e = 0; e < 16; ++e) {
      const int nr = nsub * 32 + (e & 3) + 8 * (e >> 2) + 4 * lh;
      atomicAdd(&Oacc[nr * OS + cc], oa[e]);
    }
  }
  if (lane < 32) atomicAdd(&Oacc[64 * OS + nsub * 32 + l31], den);
  __syncthreads();

  // normalize + cast -> Ol[n][c] bf16 (8 thr/row, first 512 threads)
  if (t < 512) {
    const int nloc = t >> 3, c8 = (t & 7) * 8;
    float4_t s0 = *(float4_t*)&Oacc[nloc * OS + c8];
    float4_t s1 = *(float4_t*)&Oacc[nloc * OS + c8 + 4];
    const float r = 1.0f / Oacc[64 * OS + nloc];
    uint4_t o4;
    o4[0] = pkcv(s0[0] * r, s0[1] * r);
    o4[1] = pkcv(s0[2] * r, s0[3] * r);
    o4[2] = pkcv(s1[0] * r, s1[1] * r);
    o4[3] = pkcv(s1[2] * r, s1[3] * r);
    *(uint4_t*)&Ol[nloc * OLS + c8] = o4;
  }
  __syncthreads();

  // fused proj: wave wv -> o-tile wv>>1 (32 o), n-subtile wv&1; raw fp32 W
  {
    float16_t f0 = z16();
    const float* pwrow = pw + (ms * 32 + l31) * 64 + lh * 8;
#pragma unroll
    for (int kk = 0; kk < 4; ++kk) {
      float4_t wa = *(const float4_t*)(pwrow + kk * 16);
      float4_t wb = *(const float4_t*)(pwrow + kk * 16 + 4);
      short8 af = pack8f(wa, wb);
      short8 bfr = ld8(&Ol[(nsub * 32 + l31) * OLS + kk * 16 + lh * 8]);
      f0 = MFMA(af, bfr, f0);
    }
    const int n0 = nt * 64;
#pragma unroll
    for (int e = 0; e < 16; ++e) {
      const int o = ms * 32 + (e & 3) + 8 * (e >> 2) + 4 * lh;
      const float bv = pb[o];
      out[((b * 256 + o) << 12) + n0 + nsub * 32 + l31] = f0[e] + bv;
    }
  }
}

extern "C" void kernel_launch(void* const* d_in, const int* in_sizes, int n_in,
                              void* d_out, int out_size, void* d_ws, size_t ws_size,
                              hipStream_t stream) {
  const float* x      = (const float*)d_in[0];
  const float* qkv_w  = (const float*)d_in[1];
  const float* qkv_b  = (const float*)d_in[2];
  const float* proj_w = (const float*)d_in[3];
  const float* proj_b = (const float*)d_in[4];
  float* out = (float*)d_out;

  unsigned short* ws  = (unsigned short*)d_ws;
  unsigned short* qf  = ws + QOFF;
  unsigned short* kf  = ws + KOFF;
  unsigned short* vf  = ws + VOFF;
  unsigned short* wqs = ws + WQOFF;
  float*          bs  = (float*)(ws + BSOFF);

  k_prep<<<24, 256, 0, stream>>>(qkv_w, qkv_b, wqs, bs);
  k_qkv<<<256, 768, 0, stream>>>(x, wqs, bs, qf, kf, vf);
  k_attn<<<256, 1024, 0, stream>>>(qf, kf, vf, proj_w, proj_b, out);
}

// Round 10
// 133.840 us; speedup vs baseline: 1.1042x; 1.0920x over previous
//
#include <hip/hip_runtime.h>
#include <hip/hip_bf16.h>

// EfficientAttention: x(4,256,64,64) -> qkv(192ch) -> attn(N=4096,c=64) -> proj(256ch)
// R10: attack the NON-attn 76us (iteration period 133us - k_attn 56us; k_qkv
//      est ~60us vs 3.5us roofline). k_attn reverted to R6 verbatim (best=56).
// k_prep2: blocks 0-23 = weight prep (unchanged); blocks 24+ = x fp32 ->
//      xfrag bf16 in EXACT MFMA B-frag layout [b][ch128][kk16][lane64][8]
//      (pure streaming: coalesced reads, 1KB/wave stores).
// k_qkv2 (needs +8MB ws, guarded): frag-native GEMM, NO LDS, NO barrier,
//      NO staging phase. 512 blocks x 6 waves; wave = (b, chunk, o-tile):
//      hoist wf[16] regs, stream 16 xf frags + 16 MFMA, store QKV frags.
//      6 waves/block share xf lines via L1. Fallback: R5 k_qkv if ws small.
//   Qf/Kf: [b][chunk32][kk(4)][lane(64)][8]
//   Vf   : [b][chunk32][ct(2)ks(2)][lane(64)][j(8)] = producer reg order

#define N_TOK 4096
#define CDIM  64
#define DIM   256
#define NBAT  4

typedef __attribute__((ext_vector_type(8)))  short          short8;
typedef __attribute__((ext_vector_type(8)))  unsigned short ushort8_t;
typedef __attribute__((ext_vector_type(4)))  unsigned short ushort4_t;
typedef __attribute__((ext_vector_type(4)))  unsigned int   uint4_t;
typedef __attribute__((ext_vector_type(4)))  float          float4_t;
typedef __attribute__((ext_vector_type(16))) float          float16_t;

#if __has_builtin(__builtin_amdgcn_exp2f)
#define QSC  0.18033688011112042f   /* 0.125 * log2(e): p = exp2(s) */
#define PEXP(x) __builtin_amdgcn_exp2f(x)
#else
#define QSC  0.125f
#define PEXP(x) __expf(x)
#endif

__device__ __forceinline__ unsigned short f2bf(float f) {
  unsigned int u = __builtin_bit_cast(unsigned int, f);
  u += 0x7fffu + ((u >> 16) & 1u);            // RNE
  return (unsigned short)(u >> 16);
}

// packed f32x2 -> bf16x2 dword (v_cvt_pk_bf16_f32 on gfx950, RNE)
__device__ __forceinline__ unsigned int pkcv(float a, float b) {
  __hip_bfloat162 h = __float22bfloat162_rn(make_float2(a, b));
  unsigned int r; __builtin_memcpy(&r, &h, 4); return r;
}

__device__ __forceinline__ short8 ld8(const unsigned short* p) {
  return __builtin_bit_cast(short8, *(const ushort8_t*)p);
}

__device__ __forceinline__ short8 pack8f(float4_t a, float4_t b) {
  uint4_t u;
  u[0] = pkcv(a[0], a[1]); u[1] = pkcv(a[2], a[3]);
  u[2] = pkcv(b[0], b[1]); u[3] = pkcv(b[2], b[3]);
  return __builtin_bit_cast(short8, u);
}

__device__ __forceinline__ float16_t z16() {
  float16_t r;
#pragma unroll
  for (int i = 0; i < 16; ++i) r[i] = 0.0f;
  return r;
}

// async global->LDS DMA: 64 lanes x 16B; LDS dst = wave-uniform base (+lane*16 by HW)
typedef __attribute__((address_space(1))) const void* gvp;
typedef __attribute__((address_space(3))) void*       lvp;
__device__ __forceinline__ void dma16(const unsigned short* g, unsigned short* l) {
  __builtin_amdgcn_global_load_lds((gvp)g, (lvp)l, 16, 0, 0);
}

#define MFMA(a, b, c) __builtin_amdgcn_mfma_f32_32x32x16_bf16((a), (b), (c), 0, 0, 0)

// ws layout (u16 units)
#define QOFF  0                // 4*128*4*512 = 1048576 each
#define KOFF  1048576
#define VOFF  2097152
#define WQOFF 3145728          // 192*256
#define BSOFF 3194880          // scaled qkv bias, fp32 (192)
#define XFOFF 3276800          // xfrag bf16: 4*128*16*512 = 4194304 u16 (8MB)
#define WS_NEED_U16 (XFOFF + 4194304)

// ---------------------------------------------------------------------------
// k_prep2: blocks 0-23: qkv_w -> bf16 frag layout (Q rows scaled by QSC) +
// bias fold. Blocks 24..2071: x fp32 -> xfrag bf16 B-frag layout:
//   xfrag[b][ch][kk][lane][j] = bf16( x[b][kk*16+(lane>>5)*8+j][ch*32+(lane&31)] )
// ---------------------------------------------------------------------------
__global__ void k_prep2(const float* __restrict__ x,
                        const float* __restrict__ qw, const float* __restrict__ qb,
                        unsigned short* __restrict__ wqs, float* __restrict__ bs,
                        unsigned short* __restrict__ xf)
{
  if (blockIdx.x < 24) {
    const int g = blockIdx.x * 256 + threadIdx.x;   // 0..6143
    {
      const int lane = g & 63, grp = g >> 6;
      const int w6 = grp >> 4, kk = grp & 15;
      const int o = w6 * 32 + (lane & 31);
      const int c = kk * 16 + (lane >> 5) * 8;
      const float sc = (o < 64) ? QSC : 1.0f;
      const float* src = qw + o * 256 + c;
      ushort8_t u;
#pragma unroll
      for (int j = 0; j < 8; ++j) u[j] = f2bf(src[j] * sc);
      *(ushort8_t*)(wqs + g * 8) = u;
    }
    if (g < 48) {
      float4_t f = *(const float4_t*)(qb + g * 4);
      float4_t o;
#pragma unroll
      for (int j = 0; j < 4; ++j) o[j] = f[j] * ((g * 4 + j) < 64 ? QSC : 1.0f);
      *(float4_t*)(bs + g * 4) = o;
    }
    return;
  }

  // x conversion: one thread per 16B output group
  const int idx  = (blockIdx.x - 24) * 256 + threadIdx.x;   // 0..524287
  const int lane = idx & 63;
  const int kk   = (idx >> 6) & 15;
  const int ch   = (idx >> 10) & 127;
  const int b    = (idx >> 17) & 3;
  const int n    = ch * 32 + (lane & 31);
  const int c0   = kk * 16 + (lane >> 5) * 8;
  const float* src = x + (((size_t)(b * DIM + c0)) << 12) + n;
  ushort8_t u;
#pragma unroll
  for (int j = 0; j < 8; ++j) u[j] = f2bf(src[(size_t)j << 12]);
  *(ushort8_t*)(xf + ((((size_t)(b * 128 + ch)) * 16 + kk) << 9) + lane * 8) = u;
}

// ---------------------------------------------------------------------------
// k_qkv2: grid 512 x 384 thr (6 waves). Block = (b, chunk); wave w = o-tile w.
// Frag-native: hoist wf[16] (64 VGPR), stream 16 xf frags + 16 MFMA. No LDS.
// Waves 0-3 (Q,K): C[o rows][n cols]; waves 4-5 (V): swapped operands.
// ---------------------------------------------------------------------------
__global__ __launch_bounds__(384, 2) void k_qkv2(
    const unsigned short* __restrict__ wqs, const float* __restrict__ bs,
    const unsigned short* __restrict__ xf, unsigned short* __restrict__ Qf,
    unsigned short* __restrict__ Kf, unsigned short* __restrict__ Vf)
{
  const int id = blockIdx.x;
  const int b  = id >> 7;
  const int ch = id & 127;                       // 32-token chunk
  const int t  = threadIdx.x;
  const int ot = t >> 6, lane = t & 63, l31 = lane & 31, lh = lane >> 5;

  // hoist all 16 weight frags (independent L2 loads)
  const unsigned short* wrow = wqs + ((ot * 16) << 9) + lane * 8;
  short8 wf[16];
#pragma unroll
  for (int kk = 0; kk < 16; ++kk) wf[kk] = ld8(wrow + (kk << 9));

  const unsigned short* xr = xf + (((size_t)(b * 128 + ch)) << 13) + lane * 8;

  float16_t a0 = z16();
  if (ot < 4) {
#pragma unroll
    for (int kk = 0; kk < 16; ++kk) {
      short8 xv = ld8(xr + (kk << 9));
      a0 = MFMA(wf[kk], xv, a0);                 // C[o rows][n cols]
    }
  } else {
#pragma unroll
    for (int kk = 0; kk < 16; ++kk) {
      short8 xv = ld8(xr + (kk << 9));
      a0 = MFMA(xv, wf[kk], a0);                 // C[token rows][c cols]
    }
  }

  if (ot < 4) {
    unsigned short* dst = (ot < 2) ? Qf : Kf;
    const int w2 = ot & 1;                       // c64-half of Q or K
#pragma unroll
    for (int p = 0; p < 4; ++p) {
      const int o = ot * 32 + p * 8 + lh * 4;    // global qkv channel
      float4_t bv = *(const float4_t*)(bs + o);
      ushort4_t pk4;
#pragma unroll
      for (int q = 0; q < 4; ++q) pk4[q] = f2bf(a0[p * 4 + q] + bv[q]);
      const int kkt = w2 * 2 + (p >> 1);
      *(ushort4_t*)(dst + ((((b * 128 + ch) * 4 + kkt) << 9)
                           + (l31 + 32 * (p & 1)) * 8 + lh * 4)) = pk4;
    }
  } else {
    const int ct = ot - 4;                       // c-group of V
    const float bvs = bs[128 + ct * 32 + l31];
#pragma unroll
    for (int ks = 0; ks < 2; ++ks) {
      ushort8_t pk8;
#pragma unroll
      for (int j = 0; j < 8; ++j) pk8[j] = f2bf(a0[ks * 8 + j] + bvs);
      *(ushort8_t*)(Vf + ((((b * 128 + ch) * 4 + ct * 2 + ks) << 9)
                          + lane * 8)) = pk8;
    }
  }
}

// ---------------------------------------------------------------------------
// k_qkv_fb: R5 fallback (used when ws too small for xfrag). 256 x 768 thr.
// ---------------------------------------------------------------------------
#define RS 132   // Xl row stride in dwords

__global__ __launch_bounds__(768, 3) void k_qkv_fb(
    const float* __restrict__ x, const unsigned short* __restrict__ wqs,
    const float* __restrict__ bs, unsigned short* __restrict__ Qf,
    unsigned short* __restrict__ Kf, unsigned short* __restrict__ Vf)
{
  __shared__ unsigned int Xl[64 * RS];
  const int id = blockIdx.x;
  const int b  = (id >> 1) & 3;
  const int nt = (id & 1) | ((id >> 3) << 1);   // 0..63 (64-token tile)
  const int t  = threadIdx.x;
  const int n0g = nt * 64;

  if (t < 512) {
    const int n0  = (t & 15) * 4;
    const int cpb = t >> 4;                      // 0..31
#pragma unroll
    for (int p = 0; p < 4; ++p) {
      const int cp = cpb + 32 * p, c = cp * 2;
      const float* xb = x + (((size_t)(b * DIM + c)) << 12) + n0g + n0;
      float4_t a = *(const float4_t*)xb;
      float4_t d = *(const float4_t*)(xb + 4096);
#pragma unroll
      for (int j = 0; j < 4; ++j)
        Xl[(n0 + j) * RS + cp] = pkcv(a[j], d[j]);
    }
  }

  const int w = t >> 6, lane = t & 63, l31 = lane & 31, lh = lane >> 5;
  const int ot = w >> 1, sub = w & 1;
  const int ch = nt * 2 + sub;                   // global 32-token chunk

  const unsigned short* wrow = wqs + ((ot * 16) << 9) + lane * 8;
  short8 wf[16];
#pragma unroll
  for (int kk = 0; kk < 16; ++kk) wf[kk] = ld8(wrow + (kk << 9));

  __syncthreads();

  const unsigned int* xr = &Xl[(sub * 32 + l31) * RS + lh * 4];

  float16_t a0 = z16();
  if (ot < 4) {
#pragma unroll
    for (int kk = 0; kk < 16; ++kk) {
      short8 xv = __builtin_bit_cast(short8, *(const uint4_t*)(xr + kk * 8));
      a0 = MFMA(wf[kk], xv, a0);
    }
  } else {
#pragma unroll
    for (int kk = 0; kk < 16; ++kk) {
      short8 xv = __builtin_bit_cast(short8, *(const uint4_t*)(xr + kk * 8));
      a0 = MFMA(xv, wf[kk], a0);
    }
  }

  if (ot < 4) {
    unsigned short* dst = (ot < 2) ? Qf : Kf;
    const int w2 = ot & 1;
#pragma unroll
    for (int p = 0; p < 4; ++p) {
      const int o = ot * 32 + p * 8 + lh * 4;
      float4_t bv = *(const float4_t*)(bs + o);
      ushort4_t pk4;
#pragma unroll
      for (int q = 0; q < 4; ++q) pk4[q] = f2bf(a0[p * 4 + q] + bv[q]);
      const int kkt = w2 * 2 + (p >> 1);
      *(ushort4_t*)(dst + ((((b * 128 + ch) * 4 + kkt) << 9)
                           + (l31 + 32 * (p & 1)) * 8 + lh * 4)) = pk4;
    }
  } else {
    const int ct = ot - 4;
    const float bvs = bs[128 + ct * 32 + l31];
#pragma unroll
    for (int ks = 0; ks < 2; ++ks) {
      ushort8_t pk8;
#pragma unroll
      for (int j = 0; j < 8; ++j) pk8[j] = f2bf(a0[ks * 8 + j] + bvs);
      *(ushort8_t*)(Vf + ((((b * 128 + ch) * 4 + ct * 2 + ks) << 9)
                          + lane * 8)) = pk8;
    }
  }
}

// ---------------------------------------------------------------------------
// k_attn: R6 verbatim (best measured: 56.0us). grid 256 x 512 thr (8 waves).
// Outer: 8 tiles of 512 tokens (16 chunks). K staged in LDS (2x64KB dbuf via
// global_load_lds, each wave stages chunks {2wv,2wv+1}); V read DIRECT
// global->reg per chunk (exp/pack phase covers the L2 latency).
// Compute: wave wv -> m-chunks {4mq..4mq+3} of the tile, n-subtile (wv&1).
// One barrier per tile (8 total).
// ---------------------------------------------------------------------------
#define OS   68    // Oacc row stride (fp32)
#define OLS  72    // Ol row stride (bf16)
#define NACC (64 * OS + 64)

__global__ __launch_bounds__(512, 1) void k_attn(
    const unsigned short* __restrict__ Qf, const unsigned short* __restrict__ Kf,
    const unsigned short* __restrict__ Vf, const float* __restrict__ pw,
    const float* __restrict__ pb, float* __restrict__ out)
{
  __shared__ __align__(16) unsigned short Kl[2][32768];    // [buf][16ch*2048]
  __shared__ float Oacc[NACC];                             // O[n][c] + den tail
  __shared__ __align__(16) unsigned short Ol[64 * OLS];

  const int id = blockIdx.x;
  const int b  = (id >> 1) & 3;
  const int nt = (id & 1) | ((id >> 3) << 1);        // 0..63
  const int t  = threadIdx.x;
  const int wv = t >> 6, lane = t & 63, l31 = lane & 31, lh = lane >> 5;
  const int mq = wv >> 1, nsub = wv & 1;

  for (int i = t; i < NACC; i += 512) Oacc[i] = 0.0f;

  // staging role: wave stages K chunks {2wv, 2wv+1} of each 16-chunk tile
  const int wq2 = wv * 2;
  const unsigned short* sg = Kf + (((size_t)(b * 128 + wq2)) << 11) + lane * 8;

  // Q frags (QSC pre-folded)
  short8 qf[4];
#pragma unroll
  for (int kk = 0; kk < 4; ++kk)
    qf[kk] = ld8(Qf + (((b * 128 + nt * 2 + nsub) * 4 + kk) << 9) + lane * 8);

  // V base for this batch (chunk index advances over tiles)
  const unsigned short* vbase = Vf + (((size_t)(b * 128)) << 11) + lane * 8;

  // stage tile 0 into buf 0
#pragma unroll
  for (int c2 = 0; c2 < 2; ++c2)
#pragma unroll
    for (int kk = 0; kk < 4; ++kk)
      dma16(sg + (c2 << 11) + (kk << 9),
            &Kl[0][((wq2 + c2) << 11) + (kk << 9)]);

  float16_t oc0 = z16(), oc1 = z16();
  float den = 0.0f;

  __syncthreads();   // Oacc zeroed + tile 0 resident

  for (int t8 = 0; t8 < 8; ++t8) {
    const int cur = t8 & 1;

    // stage tile t8+1 (drained at the NEXT barrier, a full tile later)
    if (t8 < 7) {
      const unsigned short* g = sg + (((size_t)(t8 + 1)) << 15);
#pragma unroll
      for (int c2 = 0; c2 < 2; ++c2)
#pragma unroll
        for (int kk = 0; kk < 4; ++kk)
          dma16(g + (c2 << 11) + (kk << 9),
                &Kl[cur ^ 1][((wq2 + c2) << 11) + (kk << 9)]);
    }

#pragma unroll
    for (int cc = 0; cc < 4; ++cc) {
      const int ch = mq * 4 + cc;                    // my m-chunk in tile
      const unsigned short* kl = &Kl[cur][ch << 11];

      short8 kf0 = ld8(kl + lane * 8);
      short8 kf1 = ld8(kl + 512 + lane * 8);
      short8 kf2 = ld8(kl + 1024 + lane * 8);
      short8 kf3 = ld8(kl + 1536 + lane * 8);

      // S^T tile: lane col n = l31, row m = (e&3)+8*(e>>2)+4*lh
      float16_t s = z16();
      s = MFMA(kf0, qf[0], s);
      s = MFMA(kf1, qf[1], s);
      s = MFMA(kf2, qf[2], s);
      s = MFMA(kf3, qf[3], s);

      float p[16];
#pragma unroll
      for (int e = 0; e < 16; ++e) p[e] = PEXP(s[e]);
      {
        float d0 = (p[0] + p[1]) + (p[2] + p[3]);
        float d1 = (p[4] + p[5]) + (p[6] + p[7]);
        float d2 = (p[8] + p[9]) + (p[10] + p[11]);
        float d3 = (p[12] + p[13]) + (p[14] + p[15]);
        den += (d0 + d1) + (d2 + d3);
      }

      // S regs ARE the O-MFMA A-operand (V k-slots pre-permuted at production)
      uint4_t w0, w1;
#pragma unroll
      for (int j = 0; j < 4; ++j) {
        w0[j] = pkcv(p[2 * j], p[2 * j + 1]);
        w1[j] = pkcv(p[8 + 2 * j], p[9 + 2 * j]);
      }
      short8 pf0 = __builtin_bit_cast(short8, w0);   // m 0..15 of chunk
      short8 pf1 = __builtin_bit_cast(short8, w1);   // m 16..31

      // V direct from global (L2-resident; exp/pack above covers latency)
      const unsigned short* vl = vbase + (((size_t)(t8 * 16 + ch)) << 11);
      short8 vf0 = ld8(vl);                          // ct0 ks0
      short8 vf1 = ld8(vl + 512);                    // ct0 ks1
      short8 vf2 = ld8(vl + 1024);                   // ct1 ks0
      short8 vf3 = ld8(vl + 1536);                   // ct1 ks1

      oc0 = MFMA(pf0, vf0, oc0);
      oc0 = MFMA(pf1, vf1, oc0);
      oc1 = MFMA(pf0, vf2, oc1);
      oc1 = MFMA(pf1, vf3, oc1);
    }

    __syncthreads();   // drains next-tile DMA + frees cur buffer
  }

  den += __shfl_xor(den, 32);   // combine lane halves (m coverage)

  // combine m-chunk partials: O[n][c] (+ den) via LDS atomics
#pragma unroll
  for (int ct = 0; ct < 2; ++ct) {
    const float16_t& oa = ct ? oc1 : oc0;
    const int cc = ct * 32 + l31;
#pragma unroll
    for (int e = 0; e < 16; ++e) {
      const int nr = nsub * 32 + (e & 3) + 8 * (e >> 2) + 4 * lh;
      atomicAdd(&Oacc[nr * OS + cc], oa[e]);
    }
  }
  if (lane < 32) atomicAdd(&Oacc[64 * OS + nsub * 32 + l31], den);
  __syncthreads();

  // normalize + cast -> Ol[n][c] bf16 (8 thr/row)
  {
    const int nloc = t >> 3, c8 = (t & 7) * 8;
    float4_t s0 = *(float4_t*)&Oacc[nloc * OS + c8];
    float4_t s1 = *(float4_t*)&Oacc[nloc * OS + c8 + 4];
    const float r = 1.0f / Oacc[64 * OS + nloc];
    uint4_t o4;
    o4[0] = pkcv(s0[0] * r, s0[1] * r);
    o4[1] = pkcv(s0[2] * r, s0[3] * r);
    o4[2] = pkcv(s1[0] * r, s1[1] * r);
    o4[3] = pkcv(s1[2] * r, s1[3] * r);
    *(uint4_t*)&Ol[nloc * OLS + c8] = o4;
  }
  __syncthreads();

  // fused proj: wave wv -> o-tile wv (32 o), both n-subtiles; raw fp32 W
  float16_t f0 = z16(), f1 = z16();
  const float* pwrow = pw + (wv * 32 + l31) * 64 + lh * 8;
#pragma unroll
  for (int kk = 0; kk < 4; ++kk) {
    float4_t wa = *(const float4_t*)(pwrow + kk * 16);
    float4_t wb = *(const float4_t*)(pwrow + kk * 16 + 4);
    short8 af = pack8f(wa, wb);
    short8 b0 = ld8(&Ol[l31 * OLS + kk * 16 + lh * 8]);
    short8 b1 = ld8(&Ol[(32 + l31) * OLS + kk * 16 + lh * 8]);
    f0 = MFMA(af, b0, f0);
    f1 = MFMA(af, b1, f1);
  }
  const int n0 = nt * 64;
#pragma unroll
  for (int e = 0; e < 16; ++e) {
    const int o = wv * 32 + (e & 3) + 8 * (e >> 2) + 4 * lh;
    const float bv = pb[o];
    out[((b * 256 + o) << 12) + n0 + l31]      = f0[e] + bv;
    out[((b * 256 + o) << 12) + n0 + 32 + l31] = f1[e] + bv;
  }
}

extern "C" void kernel_launch(void* const* d_in, const int* in_sizes, int n_in,
                              void* d_out, int out_size, void* d_ws, size_t ws_size,
                              hipStream_t stream) {
  const float* x      = (const float*)d_in[0];
  const float* qkv_w  = (const float*)d_in[1];
  const float* qkv_b  = (const float*)d_in[2];
  const float* proj_w = (const float*)d_in[3];
  const float* proj_b = (const float*)d_in[4];
  float* out = (float*)d_out;

  unsigned short* ws  = (unsigned short*)d_ws;
  unsigned short* qf  = ws + QOFF;
  unsigned short* kf  = ws + KOFF;
  unsigned short* vf  = ws + VOFF;
  unsigned short* wqs = ws + WQOFF;
  float*          bs  = (float*)(ws + BSOFF);
  unsigned short* xfr = ws + XFOFF;

  const bool big = ws_size >= (size_t)WS_NEED_U16 * 2;
  if (big) {
    k_prep2<<<2072, 256, 0, stream>>>(x, qkv_w, qkv_b, wqs, bs, xfr);
    k_qkv2<<<512, 384, 0, stream>>>(wqs, bs, xfr, qf, kf, vf);
  } else {
    k_prep2<<<24, 256, 0, stream>>>(x, qkv_w, qkv_b, wqs, bs, xfr);
    k_qkv_fb<<<256, 768, 0, stream>>>(x, wqs, bs, qf, kf, vf);
  }
  k_attn<<<256, 512, 0, stream>>>(qf, kf, vf, proj_w, proj_b, out);
}